// Round 2
// baseline (199.364 us; speedup 1.0000x reference)
//
#include <hip/hip_runtime.h>
#include <stdint.h>

typedef unsigned short u16;
typedef unsigned int   u32;
typedef short short8 __attribute__((ext_vector_type(8)));
typedef float f32x4  __attribute__((ext_vector_type(4)));

// ---------- helpers ----------
__device__ __forceinline__ u16 f2bf(float f){
  u32 u = __builtin_bit_cast(u32, f);
  u32 r = (u + 0x7FFFu + ((u >> 16) & 1u)) >> 16;   // RNE
  return (u16)r;
}
__device__ __forceinline__ u32 packbf(float a, float b){
  return (u32)f2bf(a) | ((u32)f2bf(b) << 16);
}
// async global->LDS, 16B per lane. LDS dest must be wave-uniform base + lane*16.
__device__ __forceinline__ void gload16(const u16* g, u16* l){
  __builtin_amdgcn_global_load_lds((const __attribute__((address_space(1))) void*)g,
                                   (__attribute__((address_space(3))) void*)l, 16, 0, 0);
}

// ---------- x f32 -> bf16 ----------
__global__ __launch_bounds__(256) void k_cvt_bf16(const float* __restrict__ x,
                                                  u16* __restrict__ y, int n8){
  int i = blockIdx.x * 256 + threadIdx.x;
  if (i >= n8) return;
  const float4* p = (const float4*)x + (size_t)i * 2;
  float4 a = p[0], b = p[1];
  short8 o;
  o[0] = f2bf(a.x); o[1] = f2bf(a.y); o[2] = f2bf(a.z); o[3] = f2bf(a.w);
  o[4] = f2bf(b.x); o[5] = f2bf(b.y); o[6] = f2bf(b.z); o[7] = f2bf(b.w);
  *(short8*)(y + (size_t)i * 8) = o;
}

// ---------- weight transpose: in f32[R][C] -> out bf16[C][R] ----------
__global__ __launch_bounds__(256) void k_transpose_w(const float* __restrict__ in,
                                                     u16* __restrict__ out, int R, int C){
  __shared__ float tile[32][33];
  int nc = C >> 5;
  int cb = blockIdx.x % nc, rb = blockIdx.x / nc;
  int tx = threadIdx.x & 31, ty = threadIdx.x >> 5;
#pragma unroll
  for (int i = 0; i < 4; ++i){
    int r = rb * 32 + ty + i * 8;
    tile[ty + i * 8][tx] = in[(size_t)r * C + cb * 32 + tx];
  }
  __syncthreads();
#pragma unroll
  for (int i = 0; i < 4; ++i){
    int c = cb * 32 + ty + i * 8;
    out[(size_t)c * R + rb * 32 + tx] = f2bf(tile[tx][ty + i * 8]);
  }
}

// ---------- GEMM: C[M][N] = A[M][K](bf16) * Bt[N][K](bf16)^T, fp32 accum ----------
// m97 structure: 128x128 tile, BK=32, 256 threads = 4 waves (2x2), linear LDS,
// global_load_lds width-16 staging, 2 barriers per K-step.
template<typename CT>
__global__ __launch_bounds__(256) void k_gemm_bt(const u16* __restrict__ A,
                                                 const u16* __restrict__ Bt,
                                                 CT* __restrict__ C,
                                                 int M, int N, int K){
  __shared__ u16 As[128 * 32];   // linear: required by global_load_lds (lane-contiguous dest)
  __shared__ u16 Bs[128 * 32];
  int tid  = threadIdx.x;
  int lane = tid & 63, wid = tid >> 6;
  int l16 = lane & 15, g4 = lane >> 4;
  int wm = wid >> 1, wn = wid & 1;
  int nb = N >> 7;
  int bm = blockIdx.x / nb, bn = blockIdx.x % nb;

  int rr = tid >> 2;            // row 0..63 (and +64 for second chunk)
  int cc = (tid & 3) * 8;       // ushort col within BK=32
  const u16* ga = A  + (size_t)(bm * 128 + rr) * K + cc;
  const u16* gb = Bt + (size_t)(bn * 128 + rr) * K + cc;
  u16* la = As + tid * 8;       // lds offset = tid*16B  (row rr, col cc linearized)
  u16* lb = Bs + tid * 8;
  const size_t half = (size_t)64 * K;

  f32x4 zero4 = {0.f, 0.f, 0.f, 0.f};
  f32x4 acc[4][4];
#pragma unroll
  for (int i = 0; i < 4; ++i)
#pragma unroll
    for (int j = 0; j < 4; ++j) acc[i][j] = zero4;

  int nk = K >> 5;
  for (int kt = 0; kt < nk; ++kt){
    int ko = kt * 32;
    __syncthreads();                       // prev tile's ds_reads done in all waves
    gload16(ga + ko,        la);
    gload16(ga + ko + half, la + 2048);
    gload16(gb + ko,        lb);
    gload16(gb + ko + half, lb + 2048);
    __syncthreads();                       // drains vmcnt(0): tile resident
    short8 af[4], bfr[4];
#pragma unroll
    for (int mt = 0; mt < 4; ++mt)
      af[mt] = *(const short8*)&As[(wm * 64 + mt * 16 + l16) * 32 + g4 * 8];
#pragma unroll
    for (int nt = 0; nt < 4; ++nt)
      bfr[nt] = *(const short8*)&Bs[(wn * 64 + nt * 16 + l16) * 32 + g4 * 8];
#pragma unroll
    for (int mt = 0; mt < 4; ++mt)
#pragma unroll
      for (int nt = 0; nt < 4; ++nt)
        acc[mt][nt] = __builtin_amdgcn_mfma_f32_16x16x32_bf16(af[mt], bfr[nt], acc[mt][nt], 0, 0, 0);
  }

#pragma unroll
  for (int mt = 0; mt < 4; ++mt)
#pragma unroll
    for (int nt = 0; nt < 4; ++nt)
#pragma unroll
      for (int r = 0; r < 4; ++r){
        int row = bm * 128 + wm * 64 + mt * 16 + g4 * 4 + r;
        int col = bn * 128 + wn * 64 + nt * 16 + l16;
        float vv = acc[mt][nt][r];
        if constexpr (sizeof(CT) == 2) C[(size_t)row * N + col] = (CT)f2bf(vv);
        else                           C[(size_t)row * N + col] = (CT)vv;
      }
}

// ---------- V transpose: c1 V-part [bv*256+s][2560+n*64+h] -> vt[(bv*8+n)*64+h][256 s] ----------
__global__ __launch_bounds__(256) void k_vt(const u16* __restrict__ c1, u16* __restrict__ vt){
  __shared__ u16 tile[64][72];
  int bid = blockIdx.x;
  int st = bid & 3, n = (bid >> 2) & 7, bv = bid >> 5;   // bv = b*8+v (0..15)
  int t = threadIdx.x;
  int sr = t >> 2, sc = t & 3;
  const u16* src = c1 + (size_t)(bv * 256 + st * 64 + sr) * 3072 + 2560 + n * 64 + sc * 16;
  short8 a = *(const short8*)src;
  short8 b = *(const short8*)(src + 8);
  *(short8*)&tile[sr][sc * 16]     = a;
  *(short8*)&tile[sr][sc * 16 + 8] = b;
  __syncthreads();
  int h = t >> 2, c2 = t & 3;
  short8 o0, o1;
#pragma unroll
  for (int j = 0; j < 8; ++j) o0[j] = (short)tile[c2 * 16 + j][h];
#pragma unroll
  for (int j = 0; j < 8; ++j) o1[j] = (short)tile[c2 * 16 + 8 + j][h];
  u16* dst = vt + (size_t)((bv * 8 + n) * 64 + h) * 256 + st * 64 + c2 * 16;
  *(short8*)dst       = o0;
  *(short8*)(dst + 8) = o1;
}

// ---------- fused GQA neighbor attention ----------
// block = (b, v, n, qtile64); 4 waves = 4 GQA groups sharing K/V LDS.
// swapped QK^T: mfma(K,Q) -> S^T, softmax row = lane&15; P via per-wave LDS to PV A-frag.
__global__ __launch_bounds__(256, 2) void k_attn(const u16* __restrict__ c1,
                                                 const u16* __restrict__ vt,
                                                 u16* __restrict__ att){
  __shared__ u16 Klds[64][72];       // [key][hd], pad 72
  __shared__ u16 Vlds[64][72];       // [hd][key], pad 72
  __shared__ u16 Plds[4][16][72];    // per-wave [qrow][key]
  int bid = blockIdx.x;
  int qt = bid & 3, n = (bid >> 2) & 7, v = (bid >> 5) & 7, b = bid >> 8;
  int tid = threadIdx.x;
  int g = tid >> 6, lane = tid & 63, l16 = lane & 15, g4 = lane >> 4;
  int bv = b * 8 + v;
  int rowQ = bv * 256 + qt * 64;
  int qcol = n * 256 + g * 64;
  const float SC2 = 0.18033688011112042f;   // log2(e)/8

  // hoist Q fragments (B-operand: col=qrow=l16, k=hd)
  short8 qf[4][2];
#pragma unroll
  for (int qi = 0; qi < 4; ++qi)
#pragma unroll
    for (int kk = 0; kk < 2; ++kk)
      qf[qi][kk] = *(const short8*)(c1 + (size_t)(rowQ + qi * 16 + l16) * 3072
                                     + qcol + kk * 32 + g4 * 8);

  f32x4 zero4 = {0.f, 0.f, 0.f, 0.f};
  f32x4 O[4][4];
#pragma unroll
  for (int i = 0; i < 4; ++i)
#pragma unroll
    for (int j = 0; j < 4; ++j) O[i][j] = zero4;
  float m2[4]   = {-3.0e38f, -3.0e38f, -3.0e38f, -3.0e38f};
  float lsum[4] = {0.f, 0.f, 0.f, 0.f};

  int sr = tid >> 2, sc = tid & 3;
  short8 k0, k1, v0, v1;
  {
    int vn = (v + 7) & 7;
    const u16* ks = c1 + (size_t)((b * 8 + vn) * 256 + sr) * 3072 + 2048 + n * 64 + sc * 16;
    k0 = *(const short8*)ks; k1 = *(const short8*)(ks + 8);
    const u16* vs = vt + (size_t)(((b * 8 + vn) * 8 + n) * 64 + sr) * 256 + sc * 16;
    v0 = *(const short8*)vs; v1 = *(const short8*)(vs + 8);
  }

  for (int ti = 0; ti < 8; ++ti){
    __syncthreads();
    *(short8*)&Klds[sr][sc * 16]     = k0;
    *(short8*)&Klds[sr][sc * 16 + 8] = k1;
    *(short8*)&Vlds[sr][sc * 16]     = v0;
    *(short8*)&Vlds[sr][sc * 16 + 8] = v1;
    __syncthreads();
    if (ti < 7){
      int tn = ti + 1;
      int vn = (tn < 4) ? ((v + 7) & 7) : ((v + 1) & 7);
      int tb = (tn & 3) * 64;
      const u16* ks = c1 + (size_t)((b * 8 + vn) * 256 + tb + sr) * 3072 + 2048 + n * 64 + sc * 16;
      k0 = *(const short8*)ks; k1 = *(const short8*)(ks + 8);
      const u16* vs = vt + (size_t)(((b * 8 + vn) * 8 + n) * 64 + sr) * 256 + tb + sc * 16;
      v0 = *(const short8*)vs; v1 = *(const short8*)(vs + 8);
    }
    short8 kf[4][2], vf[2][4];
#pragma unroll
    for (int kt = 0; kt < 4; ++kt)
#pragma unroll
      for (int ks = 0; ks < 2; ++ks)
        kf[kt][ks] = *(const short8*)&Klds[kt * 16 + l16][ks * 32 + g4 * 8];
#pragma unroll
    for (int ks = 0; ks < 2; ++ks)
#pragma unroll
      for (int hi = 0; hi < 4; ++hi)
        vf[ks][hi] = *(const short8*)&Vlds[hi * 16 + l16][ks * 32 + g4 * 8];

#pragma unroll
    for (int qi = 0; qi < 4; ++qi){
      f32x4 sa[4];
#pragma unroll
      for (int kt = 0; kt < 4; ++kt){
        sa[kt] = zero4;
#pragma unroll
        for (int ks = 0; ks < 2; ++ks)
          sa[kt] = __builtin_amdgcn_mfma_f32_16x16x32_bf16(kf[kt][ks], qf[qi][ks], sa[kt], 0, 0, 0);
      }
      // softmax (exp2 domain), qrow = l16; keys spread over g4 and kt
      float smax = -3.0e38f;
#pragma unroll
      for (int kt = 0; kt < 4; ++kt)
#pragma unroll
        for (int r = 0; r < 4; ++r){
          float s = sa[kt][r] * SC2;
          sa[kt][r] = s;
          smax = fmaxf(smax, s);
        }
      smax = fmaxf(smax, __shfl_xor(smax, 16));
      smax = fmaxf(smax, __shfl_xor(smax, 32));
      float mnew  = fmaxf(m2[qi], smax);
      float alpha = exp2f(m2[qi] - mnew);
      m2[qi] = mnew;
      float psum = 0.f;
      u32 w[4][2];
#pragma unroll
      for (int kt = 0; kt < 4; ++kt){
        float p0 = exp2f(sa[kt][0] - mnew);
        float p1 = exp2f(sa[kt][1] - mnew);
        float p2 = exp2f(sa[kt][2] - mnew);
        float p3 = exp2f(sa[kt][3] - mnew);
        psum += (p0 + p1) + (p2 + p3);
        w[kt][0] = packbf(p0, p1);
        w[kt][1] = packbf(p2, p3);
      }
      psum += __shfl_xor(psum, 16);
      psum += __shfl_xor(psum, 32);
      lsum[qi] = lsum[qi] * alpha + psum;
      // P -> per-wave LDS (key = kt*16 + g4*4 + {0..3}, qrow = l16)
      u32* prow = (u32*)&Plds[g][l16][0];
#pragma unroll
      for (int kt = 0; kt < 4; ++kt){
        prow[kt * 8 + g4 * 2]     = w[kt][0];
        prow[kt * 8 + g4 * 2 + 1] = w[kt][1];
      }
      // rescale O (O rows = g4*4+r -> broadcast alpha from lane g4*4+r)
      float ab[4];
#pragma unroll
      for (int r = 0; r < 4; ++r) ab[r] = __shfl(alpha, g4 * 4 + r);
#pragma unroll
      for (int hi = 0; hi < 4; ++hi)
#pragma unroll
        for (int r = 0; r < 4; ++r) O[qi][hi][r] *= ab[r];
      // PV
      short8 pa[2];
#pragma unroll
      for (int ks = 0; ks < 2; ++ks)
        pa[ks] = *(const short8*)&Plds[g][l16][ks * 32 + g4 * 8];
#pragma unroll
      for (int hi = 0; hi < 4; ++hi)
#pragma unroll
        for (int ks = 0; ks < 2; ++ks)
          O[qi][hi] = __builtin_amdgcn_mfma_f32_16x16x32_bf16(pa[ks], vf[ks][hi], O[qi][hi], 0, 0, 0);
    }
  }
  // epilogue: divide by l, write bf16
#pragma unroll
  for (int qi = 0; qi < 4; ++qi){
    float lb[4];
#pragma unroll
    for (int r = 0; r < 4; ++r) lb[r] = 1.0f / __shfl(lsum[qi], g4 * 4 + r);
#pragma unroll
    for (int hi = 0; hi < 4; ++hi)
#pragma unroll
      for (int r = 0; r < 4; ++r){
        int row = rowQ + qi * 16 + g4 * 4 + r;
        int col = qcol + hi * 16 + l16;
        att[(size_t)row * 2048 + col] = f2bf(O[qi][hi][r] * lb[r]);
      }
  }
}

extern "C" void kernel_launch(void* const* d_in, const int* in_sizes, int n_in,
                              void* d_out, int out_size, void* d_ws, size_t ws_size,
                              hipStream_t stream){
  const float* x   = (const float*)d_in[0];
  const float* wq  = (const float*)d_in[1];
  const float* wkv = (const float*)d_in[2];
  const float* wo  = (const float*)d_in[3];
  float* out = (float*)d_out;
  char* ws = (char*)d_ws;

  // workspace layout (67,108,864 B total)
  u16* x_bf  = (u16*)(ws);               // [4096][2048] bf16, 16.78 MB (aliased by att)
  u16* wqkvt = (u16*)(ws + 16777216);    // [3072][2048] bf16, 12.58 MB
  u16* wot   = (u16*)(ws + 29360128);    // [2048][2048] bf16,  8.39 MB
  u16* c1    = (u16*)(ws + 37748736);    // [4096][3072] bf16, 25.17 MB (Q|K|V)
  u16* vt    = (u16*)(ws + 62914560);    // [16*8][64][256] bf16, 4.19 MB
  u16* att   = x_bf;                     // alias: x_bf dead after GEMM1

  k_cvt_bf16<<<4096, 256, 0, stream>>>(x, x_bf, 1048576);
  k_transpose_w<<<4096, 256, 0, stream>>>(wq,  wqkvt,               2048, 2048);
  k_transpose_w<<<2048, 256, 0, stream>>>(wkv, wqkvt + 2048 * 2048, 2048, 1024);
  k_transpose_w<<<4096, 256, 0, stream>>>(wo,  wot,                 2048, 2048);
  // QKV projection: [4096,2048] x [2048,3072] -> c1 bf16
  k_gemm_bt<u16><<<768, 256, 0, stream>>>(x_bf, wqkvt, c1, 4096, 3072, 2048);
  k_vt<<<512, 256, 0, stream>>>(c1, vt);
  k_attn<<<512, 256, 0, stream>>>(c1, vt, att);
  // output projection: [4096,2048] x [2048,2048] -> f32 out
  k_gemm_bt<float><<<512, 256, 0, stream>>>(att, wot, out, 4096, 2048, 2048);
}

// Round 3
// 189.722 us; speedup vs baseline: 1.0508x; 1.0508x over previous
//
#include <hip/hip_runtime.h>
#include <stdint.h>

typedef unsigned short u16;
typedef unsigned int   u32;
typedef short short8 __attribute__((ext_vector_type(8)));
typedef float f32x4  __attribute__((ext_vector_type(4)));

// ---------- helpers ----------
__device__ __forceinline__ u16 f2bf(float f){
  u32 u = __builtin_bit_cast(u32, f);
  u32 r = (u + 0x7FFFu + ((u >> 16) & 1u)) >> 16;   // RNE
  return (u16)r;
}
__device__ __forceinline__ u32 packbf(float a, float b){
  return (u32)f2bf(a) | ((u32)f2bf(b) << 16);
}
// async global->LDS, 16B per lane. LDS dest = wave-uniform base + lane*16.
__device__ __forceinline__ void gload16(const u16* g, u16* l){
  __builtin_amdgcn_global_load_lds((const __attribute__((address_space(1))) void*)g,
                                   (__attribute__((address_space(3))) void*)l, 16, 0, 0);
}

// ---------- x f32 -> bf16 ----------
__global__ __launch_bounds__(256) void k_cvt_bf16(const float* __restrict__ x,
                                                  u16* __restrict__ y, int n8){
  int i = blockIdx.x * 256 + threadIdx.x;
  if (i >= n8) return;
  const float4* p = (const float4*)x + (size_t)i * 2;
  float4 a = p[0], b = p[1];
  short8 o;
  o[0] = f2bf(a.x); o[1] = f2bf(a.y); o[2] = f2bf(a.z); o[3] = f2bf(a.w);
  o[4] = f2bf(b.x); o[5] = f2bf(b.y); o[6] = f2bf(b.z); o[7] = f2bf(b.w);
  *(short8*)(y + (size_t)i * 8) = o;
}

// ---------- weight transpose: in f32[R][C] -> out bf16[C][R] ----------
__global__ __launch_bounds__(256) void k_transpose_w(const float* __restrict__ in,
                                                     u16* __restrict__ out, int R, int C){
  __shared__ float tile[32][33];
  int nc = C >> 5;
  int cb = blockIdx.x % nc, rb = blockIdx.x / nc;
  int tx = threadIdx.x & 31, ty = threadIdx.x >> 5;
#pragma unroll
  for (int i = 0; i < 4; ++i){
    int r = rb * 32 + ty + i * 8;
    tile[ty + i * 8][tx] = in[(size_t)r * C + cb * 32 + tx];
  }
  __syncthreads();
#pragma unroll
  for (int i = 0; i < 4; ++i){
    int c = cb * 32 + ty + i * 8;
    out[(size_t)c * R + rb * 32 + tx] = f2bf(tile[tx][ty + i * 8]);
  }
}

// ---------- GEMM: C[M][N] = A[M][K](bf16) * Bt[N][K](bf16)^T, fp32 accum ----------
// T3 2-phase: 2x2 wave grid, BM=32*MREP, BN=32*NREP, BK=32, double-buffered LDS,
// global_load_lds width-16 staging of tile t+1 issued BEFORE computing tile t,
// ONE __syncthreads per K-step (drains both lgkm (ds_reads) and vm (staged loads)).
template<int MREP, int NREP, typename CT>
__global__ __launch_bounds__(256) void k_gemm_bt(const u16* __restrict__ A,
                                                 const u16* __restrict__ Bt,
                                                 CT* __restrict__ C,
                                                 int M, int N, int K){
  constexpr int BM = 32 * MREP, BN = 32 * NREP;
  constexpr int ASZ = BM * 32, BSZ = BN * 32;   // u16 elems per buffer
  __shared__ u16 As[2 * ASZ];
  __shared__ u16 Bs[2 * BSZ];
  int tid  = threadIdx.x;
  int lane = tid & 63, wid = tid >> 6;
  int l16 = lane & 15, g4 = lane >> 4;
  int wm = wid >> 1, wn = wid & 1;
  int nb = N / BN;
  int bm = blockIdx.x / nb, bn = blockIdx.x % nb;

  int rr = tid >> 2;            // staging row (0..63 per 64-row chunk)
  int cc = (tid & 3) * 8;       // staging ushort col within BK=32
  const u16* ga = A  + (size_t)(bm * BM + rr) * K + cc;
  const u16* gb = Bt + (size_t)(bn * BN + rr) * K + cc;

  f32x4 zero4 = {0.f, 0.f, 0.f, 0.f};
  f32x4 acc[MREP][NREP];
#pragma unroll
  for (int i = 0; i < MREP; ++i)
#pragma unroll
    for (int j = 0; j < NREP; ++j) acc[i][j] = zero4;

  int nk = K >> 5;
  // prologue: stage tile 0 into buffer 0
#pragma unroll
  for (int h = 0; h < BM / 64; ++h) gload16(ga + (size_t)h * 64 * K, As + tid * 8 + h * 2048);
#pragma unroll
  for (int h = 0; h < BN / 64; ++h) gload16(gb + (size_t)h * 64 * K, Bs + tid * 8 + h * 2048);
  __syncthreads();

  int cur = 0;
  for (int kt = 0; kt < nk; ++kt){
    if (kt + 1 < nk){            // stage tile kt+1 into the other buffer (overlaps MFMA below)
      int ko = (kt + 1) * 32;
      u16* la = As + (cur ^ 1) * ASZ + tid * 8;
      u16* lb = Bs + (cur ^ 1) * BSZ + tid * 8;
#pragma unroll
      for (int h = 0; h < BM / 64; ++h) gload16(ga + ko + (size_t)h * 64 * K, la + h * 2048);
#pragma unroll
      for (int h = 0; h < BN / 64; ++h) gload16(gb + ko + (size_t)h * 64 * K, lb + h * 2048);
    }
    const u16* ab = As + cur * ASZ;
    const u16* bb = Bs + cur * BSZ;
    short8 af[MREP], bfr[NREP];
#pragma unroll
    for (int mt = 0; mt < MREP; ++mt)
      af[mt] = *(const short8*)&ab[(wm * (BM / 2) + mt * 16 + l16) * 32 + g4 * 8];
#pragma unroll
    for (int nt = 0; nt < NREP; ++nt)
      bfr[nt] = *(const short8*)&bb[(wn * (BN / 2) + nt * 16 + l16) * 32 + g4 * 8];
#pragma unroll
    for (int mt = 0; mt < MREP; ++mt)
#pragma unroll
      for (int nt = 0; nt < NREP; ++nt)
        acc[mt][nt] = __builtin_amdgcn_mfma_f32_16x16x32_bf16(af[mt], bfr[nt], acc[mt][nt], 0, 0, 0);
    __syncthreads();             // drains this wave's vm (stage) + lgkm (ds_read); all waves synced
    cur ^= 1;
  }

#pragma unroll
  for (int mt = 0; mt < MREP; ++mt)
#pragma unroll
    for (int nt = 0; nt < NREP; ++nt)
#pragma unroll
      for (int r = 0; r < 4; ++r){
        int row = bm * BM + wm * (BM / 2) + mt * 16 + g4 * 4 + r;
        int col = bn * BN + wn * (BN / 2) + nt * 16 + l16;
        float vv = acc[mt][nt][r];
        if constexpr (sizeof(CT) == 2) C[(size_t)row * N + col] = (CT)f2bf(vv);
        else                           C[(size_t)row * N + col] = (CT)vv;
      }
}

// ---------- V transpose: c1 V-part [bv*256+s][2560+n*64+h] -> vt[(bv*8+n)*64+h][256 s] ----------
__global__ __launch_bounds__(256) void k_vt(const u16* __restrict__ c1, u16* __restrict__ vt){
  __shared__ u16 tile[64][72];
  int bid = blockIdx.x;
  int st = bid & 3, n = (bid >> 2) & 7, bv = bid >> 5;   // bv = b*8+v (0..15)
  int t = threadIdx.x;
  int sr = t >> 2, sc = t & 3;
  const u16* src = c1 + (size_t)(bv * 256 + st * 64 + sr) * 3072 + 2560 + n * 64 + sc * 16;
  short8 a = *(const short8*)src;
  short8 b = *(const short8*)(src + 8);
  *(short8*)&tile[sr][sc * 16]     = a;
  *(short8*)&tile[sr][sc * 16 + 8] = b;
  __syncthreads();
  int h = t >> 2, c2 = t & 3;
  short8 o0, o1;
#pragma unroll
  for (int j = 0; j < 8; ++j) o0[j] = (short)tile[c2 * 16 + j][h];
#pragma unroll
  for (int j = 0; j < 8; ++j) o1[j] = (short)tile[c2 * 16 + 8 + j][h];
  u16* dst = vt + (size_t)((bv * 8 + n) * 64 + h) * 256 + st * 64 + c2 * 16;
  *(short8*)dst       = o0;
  *(short8*)(dst + 8) = o1;
}

// ---------- fused GQA neighbor attention ----------
// block = (b, v, n, qtile64); 4 waves = 4 GQA groups sharing K/V LDS.
// swapped QK^T: mfma(K,Q) -> S^T, softmax row = lane&15; P via per-wave LDS to PV A-frag.
__global__ __launch_bounds__(256, 2) void k_attn(const u16* __restrict__ c1,
                                                 const u16* __restrict__ vt,
                                                 u16* __restrict__ att){
  __shared__ u16 Klds[64][72];       // [key][hd], pad 72
  __shared__ u16 Vlds[64][72];       // [hd][key], pad 72
  __shared__ u16 Plds[4][16][72];    // per-wave [qrow][key]
  int bid = blockIdx.x;
  int qt = bid & 3, n = (bid >> 2) & 7, v = (bid >> 5) & 7, b = bid >> 8;
  int tid = threadIdx.x;
  int g = tid >> 6, lane = tid & 63, l16 = lane & 15, g4 = lane >> 4;
  int bv = b * 8 + v;
  int rowQ = bv * 256 + qt * 64;
  int qcol = n * 256 + g * 64;
  const float SC2 = 0.18033688011112042f;   // log2(e)/8

  // hoist Q fragments (B-operand: col=qrow=l16, k=hd)
  short8 qf[4][2];
#pragma unroll
  for (int qi = 0; qi < 4; ++qi)
#pragma unroll
    for (int kk = 0; kk < 2; ++kk)
      qf[qi][kk] = *(const short8*)(c1 + (size_t)(rowQ + qi * 16 + l16) * 3072
                                     + qcol + kk * 32 + g4 * 8);

  f32x4 zero4 = {0.f, 0.f, 0.f, 0.f};
  f32x4 O[4][4];
#pragma unroll
  for (int i = 0; i < 4; ++i)
#pragma unroll
    for (int j = 0; j < 4; ++j) O[i][j] = zero4;
  float m2[4]   = {-3.0e38f, -3.0e38f, -3.0e38f, -3.0e38f};
  float lsum[4] = {0.f, 0.f, 0.f, 0.f};

  int sr = tid >> 2, sc = tid & 3;
  short8 k0, k1, v0, v1;
  {
    int vn = (v + 7) & 7;
    const u16* ks = c1 + (size_t)((b * 8 + vn) * 256 + sr) * 3072 + 2048 + n * 64 + sc * 16;
    k0 = *(const short8*)ks; k1 = *(const short8*)(ks + 8);
    const u16* vs = vt + (size_t)(((b * 8 + vn) * 8 + n) * 64 + sr) * 256 + sc * 16;
    v0 = *(const short8*)vs; v1 = *(const short8*)(vs + 8);
  }

  for (int ti = 0; ti < 8; ++ti){
    __syncthreads();
    *(short8*)&Klds[sr][sc * 16]     = k0;
    *(short8*)&Klds[sr][sc * 16 + 8] = k1;
    *(short8*)&Vlds[sr][sc * 16]     = v0;
    *(short8*)&Vlds[sr][sc * 16 + 8] = v1;
    __syncthreads();
    if (ti < 7){
      int tn = ti + 1;
      int vn = (tn < 4) ? ((v + 7) & 7) : ((v + 1) & 7);
      int tb = (tn & 3) * 64;
      const u16* ks = c1 + (size_t)((b * 8 + vn) * 256 + tb + sr) * 3072 + 2048 + n * 64 + sc * 16;
      k0 = *(const short8*)ks; k1 = *(const short8*)(ks + 8);
      const u16* vs = vt + (size_t)(((b * 8 + vn) * 8 + n) * 64 + sr) * 256 + tb + sc * 16;
      v0 = *(const short8*)vs; v1 = *(const short8*)(vs + 8);
    }
    short8 kf[4][2], vf[2][4];
#pragma unroll
    for (int kt = 0; kt < 4; ++kt)
#pragma unroll
      for (int ks = 0; ks < 2; ++ks)
        kf[kt][ks] = *(const short8*)&Klds[kt * 16 + l16][ks * 32 + g4 * 8];
#pragma unroll
    for (int ks = 0; ks < 2; ++ks)
#pragma unroll
      for (int hi = 0; hi < 4; ++hi)
        vf[ks][hi] = *(const short8*)&Vlds[hi * 16 + l16][ks * 32 + g4 * 8];

#pragma unroll
    for (int qi = 0; qi < 4; ++qi){
      f32x4 sa[4];
#pragma unroll
      for (int kt = 0; kt < 4; ++kt){
        sa[kt] = zero4;
#pragma unroll
        for (int ks = 0; ks < 2; ++ks)
          sa[kt] = __builtin_amdgcn_mfma_f32_16x16x32_bf16(kf[kt][ks], qf[qi][ks], sa[kt], 0, 0, 0);
      }
      // softmax (exp2 domain), qrow = l16; keys spread over g4 and kt
      float smax = -3.0e38f;
#pragma unroll
      for (int kt = 0; kt < 4; ++kt)
#pragma unroll
        for (int r = 0; r < 4; ++r){
          float s = sa[kt][r] * SC2;
          sa[kt][r] = s;
          smax = fmaxf(smax, s);
        }
      smax = fmaxf(smax, __shfl_xor(smax, 16));
      smax = fmaxf(smax, __shfl_xor(smax, 32));
      float mnew  = fmaxf(m2[qi], smax);
      float alpha = exp2f(m2[qi] - mnew);
      m2[qi] = mnew;
      float psum = 0.f;
      u32 w[4][2];
#pragma unroll
      for (int kt = 0; kt < 4; ++kt){
        float p0 = exp2f(sa[kt][0] - mnew);
        float p1 = exp2f(sa[kt][1] - mnew);
        float p2 = exp2f(sa[kt][2] - mnew);
        float p3 = exp2f(sa[kt][3] - mnew);
        psum += (p0 + p1) + (p2 + p3);
        w[kt][0] = packbf(p0, p1);
        w[kt][1] = packbf(p2, p3);
      }
      psum += __shfl_xor(psum, 16);
      psum += __shfl_xor(psum, 32);
      lsum[qi] = lsum[qi] * alpha + psum;
      // P -> per-wave LDS (key = kt*16 + g4*4 + {0..3}, qrow = l16)
      u32* prow = (u32*)&Plds[g][l16][0];
#pragma unroll
      for (int kt = 0; kt < 4; ++kt){
        prow[kt * 8 + g4 * 2]     = w[kt][0];
        prow[kt * 8 + g4 * 2 + 1] = w[kt][1];
      }
      // rescale O (O rows = g4*4+r -> broadcast alpha from lane g4*4+r)
      float ab[4];
#pragma unroll
      for (int r = 0; r < 4; ++r) ab[r] = __shfl(alpha, g4 * 4 + r);
#pragma unroll
      for (int hi = 0; hi < 4; ++hi)
#pragma unroll
        for (int r = 0; r < 4; ++r) O[qi][hi][r] *= ab[r];
      // PV
      short8 pa[2];
#pragma unroll
      for (int ks = 0; ks < 2; ++ks)
        pa[ks] = *(const short8*)&Plds[g][l16][ks * 32 + g4 * 8];
#pragma unroll
      for (int hi = 0; hi < 4; ++hi)
#pragma unroll
        for (int ks = 0; ks < 2; ++ks)
          O[qi][hi] = __builtin_amdgcn_mfma_f32_16x16x32_bf16(pa[ks], vf[ks][hi], O[qi][hi], 0, 0, 0);
    }
  }
  // epilogue: divide by l, write bf16
#pragma unroll
  for (int qi = 0; qi < 4; ++qi){
    float lb[4];
#pragma unroll
    for (int r = 0; r < 4; ++r) lb[r] = 1.0f / __shfl(lsum[qi], g4 * 4 + r);
#pragma unroll
    for (int hi = 0; hi < 4; ++hi)
#pragma unroll
      for (int r = 0; r < 4; ++r){
        int row = rowQ + qi * 16 + g4 * 4 + r;
        int col = qcol + hi * 16 + l16;
        att[(size_t)row * 2048 + col] = f2bf(O[qi][hi][r] * lb[r]);
      }
  }
}

extern "C" void kernel_launch(void* const* d_in, const int* in_sizes, int n_in,
                              void* d_out, int out_size, void* d_ws, size_t ws_size,
                              hipStream_t stream){
  const float* x   = (const float*)d_in[0];
  const float* wq  = (const float*)d_in[1];
  const float* wkv = (const float*)d_in[2];
  const float* wo  = (const float*)d_in[3];
  float* out = (float*)d_out;
  char* ws = (char*)d_ws;

  // workspace layout (67,108,864 B total)
  u16* x_bf  = (u16*)(ws);               // [4096][2048] bf16, 16.78 MB (aliased by att)
  u16* wqkvt = (u16*)(ws + 16777216);    // [3072][2048] bf16, 12.58 MB
  u16* wot   = (u16*)(ws + 29360128);    // [2048][2048] bf16,  8.39 MB
  u16* c1    = (u16*)(ws + 37748736);    // [4096][3072] bf16, 25.17 MB (Q|K|V)
  u16* vt    = (u16*)(ws + 62914560);    // [16*8][64][256] bf16, 4.19 MB
  u16* att   = x_bf;                     // alias: x_bf dead after GEMM1

  k_cvt_bf16<<<4096, 256, 0, stream>>>(x, x_bf, 1048576);
  k_transpose_w<<<4096, 256, 0, stream>>>(wq,  wqkvt,               2048, 2048);
  k_transpose_w<<<2048, 256, 0, stream>>>(wkv, wqkvt + 2048 * 2048, 2048, 1024);
  k_transpose_w<<<4096, 256, 0, stream>>>(wo,  wot,                 2048, 2048);
  // QKV projection: [4096,2048] x [2048,3072] -> c1 bf16, 128x128 tiles, 768 blocks
  k_gemm_bt<4, 4, u16><<<768, 256, 0, stream>>>(x_bf, wqkvt, c1, 4096, 3072, 2048);
  k_vt<<<512, 256, 0, stream>>>(c1, vt);
  k_attn<<<512, 256, 0, stream>>>(c1, vt, att);
  // output projection: [4096,2048] x [2048,2048] -> f32 out, 64x128 tiles, 1024 blocks
  k_gemm_bt<2, 4, float><<<1024, 256, 0, stream>>>(att, wot, out, 4096, 2048, 2048);
}

// Round 4
// 169.440 us; speedup vs baseline: 1.1766x; 1.1197x over previous
//
#include <hip/hip_runtime.h>
#include <stdint.h>

typedef unsigned short u16;
typedef unsigned int   u32;
typedef short short8 __attribute__((ext_vector_type(8)));
typedef float f32x4  __attribute__((ext_vector_type(4)));

// ---------- helpers ----------
__device__ __forceinline__ u16 f2bf(float f){
  u32 u = __builtin_bit_cast(u32, f);
  u32 r = (u + 0x7FFFu + ((u >> 16) & 1u)) >> 16;   // RNE
  return (u16)r;
}
__device__ __forceinline__ u32 packbf(float a, float b){
  return (u32)f2bf(a) | ((u32)f2bf(b) << 16);
}
// async global->LDS, 16B per lane. LDS dest = wave-uniform base + lane*16.
__device__ __forceinline__ void gload16(const u16* g, u16* l){
  __builtin_amdgcn_global_load_lds((const __attribute__((address_space(1))) void*)g,
                                   (__attribute__((address_space(3))) void*)l, 16, 0, 0);
}

// ---------- x f32 -> bf16 ----------
__global__ __launch_bounds__(256) void k_cvt_bf16(const float* __restrict__ x,
                                                  u16* __restrict__ y, int n8){
  int i = blockIdx.x * 256 + threadIdx.x;
  if (i >= n8) return;
  const float4* p = (const float4*)x + (size_t)i * 2;
  float4 a = p[0], b = p[1];
  short8 o;
  o[0] = f2bf(a.x); o[1] = f2bf(a.y); o[2] = f2bf(a.z); o[3] = f2bf(a.w);
  o[4] = f2bf(b.x); o[5] = f2bf(b.y); o[6] = f2bf(b.z); o[7] = f2bf(b.w);
  *(short8*)(y + (size_t)i * 8) = o;
}

// ---------- weight transpose: in f32[R][C] -> out bf16[C][R] ----------
__global__ __launch_bounds__(256) void k_transpose_w(const float* __restrict__ in,
                                                     u16* __restrict__ out, int R, int C){
  __shared__ float tile[32][33];
  int nc = C >> 5;
  int cb = blockIdx.x % nc, rb = blockIdx.x / nc;
  int tx = threadIdx.x & 31, ty = threadIdx.x >> 5;
#pragma unroll
  for (int i = 0; i < 4; ++i){
    int r = rb * 32 + ty + i * 8;
    tile[ty + i * 8][tx] = in[(size_t)r * C + cb * 32 + tx];
  }
  __syncthreads();
#pragma unroll
  for (int i = 0; i < 4; ++i){
    int c = cb * 32 + ty + i * 8;
    out[(size_t)c * R + rb * 32 + tx] = f2bf(tile[tx][ty + i * 8]);
  }
}

// ---------- pipelined GEMM: C[4096][N] = A[4096][K] * Bt[N][K]^T, bf16 in, f32 accum ----
// 512 threads = 8 waves (2m x 4n). BM=256, BN=192/128, BK=32.
// 4 LDS K-tile buffers; stage kt+3 during kt (counted vmcnt(6), raw barriers, T2 swizzle,
// T5 setprio). Race-free: buffer (kt+3)%4 last read at K-tile kt-1, before kt's entry barrier.
template<int BN, int NFRAG, typename CT>
__global__ __launch_bounds__(512, 1) void k_gemm8(const u16* __restrict__ A,
                                                  const u16* __restrict__ Bt,
                                                  CT* __restrict__ C,
                                                  int N, int K){
  constexpr int SZA = 256 * 64;          // A region bytes per buffer (256 rows x 64B)
  constexpr int SZB = BN * 64;
  constexpr int SZ  = SZA + SZB;
  constexpr int BSLICES = SZB / 1024;    // 12 (QKV) or 8 (O-proj) 1-KB wave slices
  constexpr int WT_N = BN / 4;           // wave-tile n extent
  __shared__ u16 lds[4 * SZ / 2];

  int tid = threadIdx.x, lane = tid & 63, wid = tid >> 6;
  int l16 = lane & 15, g4 = lane >> 4;
  int wm = wid >> 2, wn = wid & 3;
  // XCD swizzle: 256 blocks, 8 XCDs -> 32 contiguous wg per XCD (2 bm-rows x 16 bn)
  int bid = blockIdx.x;
  int wg = (bid & 7) * 32 + (bid >> 3);
  int bm = wg >> 4, bn = wg & 15;

  const u16* baseA = A  + (size_t)(bm * 256) * K;
  const u16* baseB = Bt + (size_t)(bn * BN) * K;

  // staging maps: LDS write is LINEAR (q); global source is inverse-swizzled
  // (c' = c ^ ((row&3)<<4), involution). Reads apply the same XOR.
  int aq[2], ag[2];
#pragma unroll
  for (int i = 0; i < 2; ++i){
    int q = (i * 8 + wid) * 1024 + lane * 16;
    int row = q >> 6, c = q & 63;
    int cs = c ^ ((row & 3) << 4);
    aq[i] = q; ag[i] = row * K + (cs >> 1);
  }
  int bq[2], bg[2];
#pragma unroll
  for (int j = 0; j < 2; ++j){
    int slice = wid + j * 8;
    int q = slice * 1024 + lane * 16;
    int row = q >> 6, c = q & 63;
    int cs = c ^ ((row & 3) << 4);
    bq[j] = q; bg[j] = row * K + (cs >> 1);
  }

  auto stageA = [&](int kt3, int i){
    int buf = kt3 & 3;
    gload16(baseA + ag[i] + kt3 * 32, (u16*)((char*)lds + buf * SZ + aq[i]));
  };
  auto stageB = [&](int kt3, int j){
    int buf = kt3 & 3;
    gload16(baseB + bg[j] + kt3 * 32, (u16*)((char*)lds + buf * SZ + SZA + bq[j]));
  };

  f32x4 zero4 = {0.f, 0.f, 0.f, 0.f};
  f32x4 acc[8][NFRAG];
#pragma unroll
  for (int i = 0; i < 8; ++i)
#pragma unroll
    for (int j = 0; j < NFRAG; ++j) acc[i][j] = zero4;

  int NK = K >> 5;
  // prologue: stage K-tiles 0,1,2
  for (int p = 0; p < 3; ++p){
    stageA(p, 0); stageB(p, 0);
    stageA(p, 1);
    if (wid < BSLICES - 8) stageB(p, 1);
  }

  int xr = (l16 & 3) << 4;
  for (int kt = 0; kt < NK; ++kt){
    // entry wait: counted vmcnt (own loads for kt complete; kt+1/kt+2 stay in flight)
    if (kt < NK - 2)       asm volatile("s_waitcnt vmcnt(6)" ::: "memory");
    else if (kt == NK - 2) asm volatile("s_waitcnt vmcnt(3)" ::: "memory");
    else                   asm volatile("s_waitcnt vmcnt(0)" ::: "memory");
    __builtin_amdgcn_s_barrier();
    __builtin_amdgcn_sched_barrier(0);

    const char* Ab = (const char*)lds + (kt & 3) * SZ;
    const char* Bb = Ab + SZA;
    bool st = (kt + 3 < NK);

    // B fragments (whole K-tile) + A fragments m0-3
    short8 bfr[NFRAG];
#pragma unroll
    for (int nf = 0; nf < NFRAG; ++nf){
      int row = wn * WT_N + nf * 16 + l16;
      bfr[nf] = *(const short8*)(Bb + row * 64 + ((g4 * 16) ^ xr));
    }
    short8 af[4];
#pragma unroll
    for (int mf = 0; mf < 4; ++mf){
      int row = wm * 128 + mf * 16 + l16;
      af[mf] = *(const short8*)(Ab + row * 64 + ((g4 * 16) ^ xr));
    }
    if (st){ stageA(kt + 3, 0); stageB(kt + 3, 0); }
    __builtin_amdgcn_s_setprio(1);
#pragma unroll
    for (int mf = 0; mf < 4; ++mf)
#pragma unroll
      for (int nf = 0; nf < NFRAG; ++nf)
        acc[mf][nf] = __builtin_amdgcn_mfma_f32_16x16x32_bf16(af[mf], bfr[nf], acc[mf][nf], 0, 0, 0);
    __builtin_amdgcn_s_setprio(0);
    __builtin_amdgcn_s_barrier();
    __builtin_amdgcn_sched_barrier(0);

    // A fragments m4-7
#pragma unroll
    for (int mf = 0; mf < 4; ++mf){
      int row = wm * 128 + 64 + mf * 16 + l16;
      af[mf] = *(const short8*)(Ab + row * 64 + ((g4 * 16) ^ xr));
    }
    if (st){ stageA(kt + 3, 1); if (wid < BSLICES - 8) stageB(kt + 3, 1); }
    __builtin_amdgcn_s_setprio(1);
#pragma unroll
    for (int mf = 0; mf < 4; ++mf)
#pragma unroll
      for (int nf = 0; nf < NFRAG; ++nf)
        acc[4 + mf][nf] = __builtin_amdgcn_mfma_f32_16x16x32_bf16(af[mf], bfr[nf], acc[4 + mf][nf], 0, 0, 0);
    __builtin_amdgcn_s_setprio(0);
  }

#pragma unroll
  for (int mf = 0; mf < 8; ++mf)
#pragma unroll
    for (int nf = 0; nf < NFRAG; ++nf)
#pragma unroll
      for (int r = 0; r < 4; ++r){
        int row = bm * 256 + wm * 128 + mf * 16 + g4 * 4 + r;
        int col = bn * BN + wn * WT_N + nf * 16 + l16;
        float vv = acc[mf][nf][r];
        if constexpr (sizeof(CT) == 2) C[(size_t)row * N + col] = (CT)f2bf(vv);
        else                           C[(size_t)row * N + col] = (CT)vv;
      }
}

// ---------- V transpose: c1 V-part [bv*256+s][2560+n*64+h] -> vt[(bv*8+n)*64+h][256 s] ----------
__global__ __launch_bounds__(256) void k_vt(const u16* __restrict__ c1, u16* __restrict__ vt){
  __shared__ u16 tile[64][72];
  int bid = blockIdx.x;
  int st = bid & 3, n = (bid >> 2) & 7, bv = bid >> 5;   // bv = b*8+v (0..15)
  int t = threadIdx.x;
  int sr = t >> 2, sc = t & 3;
  const u16* src = c1 + (size_t)(bv * 256 + st * 64 + sr) * 3072 + 2560 + n * 64 + sc * 16;
  short8 a = *(const short8*)src;
  short8 b = *(const short8*)(src + 8);
  *(short8*)&tile[sr][sc * 16]     = a;
  *(short8*)&tile[sr][sc * 16 + 8] = b;
  __syncthreads();
  int h = t >> 2, c2 = t & 3;
  short8 o0, o1;
#pragma unroll
  for (int j = 0; j < 8; ++j) o0[j] = (short)tile[c2 * 16 + j][h];
#pragma unroll
  for (int j = 0; j < 8; ++j) o1[j] = (short)tile[c2 * 16 + 8 + j][h];
  u16* dst = vt + (size_t)((bv * 8 + n) * 64 + h) * 256 + st * 64 + c2 * 16;
  *(short8*)dst       = o0;
  *(short8*)(dst + 8) = o1;
}

// ---------- fused GQA neighbor attention ----------
// block = (b, v, n, qtile64); 4 waves = 4 GQA groups sharing K/V LDS.
// swapped QK^T: mfma(K,Q) -> S^T, softmax row = lane&15; P via per-wave LDS to PV A-frag.
__global__ __launch_bounds__(256, 2) void k_attn(const u16* __restrict__ c1,
                                                 const u16* __restrict__ vt,
                                                 u16* __restrict__ att){
  __shared__ u16 Klds[64][72];       // [key][hd], pad 72
  __shared__ u16 Vlds[64][72];       // [hd][key], pad 72
  __shared__ u16 Plds[4][16][72];    // per-wave [qrow][key]
  int bid = blockIdx.x;
  int qt = bid & 3, n = (bid >> 2) & 7, v = (bid >> 5) & 7, b = bid >> 8;
  int tid = threadIdx.x;
  int g = tid >> 6, lane = tid & 63, l16 = lane & 15, g4 = lane >> 4;
  int bv = b * 8 + v;
  int rowQ = bv * 256 + qt * 64;
  int qcol = n * 256 + g * 64;
  const float SC2 = 0.18033688011112042f;   // log2(e)/8

  short8 qf[4][2];
#pragma unroll
  for (int qi = 0; qi < 4; ++qi)
#pragma unroll
    for (int kk = 0; kk < 2; ++kk)
      qf[qi][kk] = *(const short8*)(c1 + (size_t)(rowQ + qi * 16 + l16) * 3072
                                     + qcol + kk * 32 + g4 * 8);

  f32x4 zero4 = {0.f, 0.f, 0.f, 0.f};
  f32x4 O[4][4];
#pragma unroll
  for (int i = 0; i < 4; ++i)
#pragma unroll
    for (int j = 0; j < 4; ++j) O[i][j] = zero4;
  float m2[4]   = {-3.0e38f, -3.0e38f, -3.0e38f, -3.0e38f};
  float lsum[4] = {0.f, 0.f, 0.f, 0.f};

  int sr = tid >> 2, sc = tid & 3;
  short8 k0, k1, v0, v1;
  {
    int vn = (v + 7) & 7;
    const u16* ks = c1 + (size_t)((b * 8 + vn) * 256 + sr) * 3072 + 2048 + n * 64 + sc * 16;
    k0 = *(const short8*)ks; k1 = *(const short8*)(ks + 8);
    const u16* vs = vt + (size_t)(((b * 8 + vn) * 8 + n) * 64 + sr) * 256 + sc * 16;
    v0 = *(const short8*)vs; v1 = *(const short8*)(vs + 8);
  }

  for (int ti = 0; ti < 8; ++ti){
    __syncthreads();
    *(short8*)&Klds[sr][sc * 16]     = k0;
    *(short8*)&Klds[sr][sc * 16 + 8] = k1;
    *(short8*)&Vlds[sr][sc * 16]     = v0;
    *(short8*)&Vlds[sr][sc * 16 + 8] = v1;
    __syncthreads();
    if (ti < 7){
      int tn = ti + 1;
      int vn = (tn < 4) ? ((v + 7) & 7) : ((v + 1) & 7);
      int tb = (tn & 3) * 64;
      const u16* ks = c1 + (size_t)((b * 8 + vn) * 256 + tb + sr) * 3072 + 2048 + n * 64 + sc * 16;
      k0 = *(const short8*)ks; k1 = *(const short8*)(ks + 8);
      const u16* vs = vt + (size_t)(((b * 8 + vn) * 8 + n) * 64 + sr) * 256 + tb + sc * 16;
      v0 = *(const short8*)vs; v1 = *(const short8*)(vs + 8);
    }
    short8 kf[4][2], vf[2][4];
#pragma unroll
    for (int kt = 0; kt < 4; ++kt)
#pragma unroll
      for (int ks = 0; ks < 2; ++ks)
        kf[kt][ks] = *(const short8*)&Klds[kt * 16 + l16][ks * 32 + g4 * 8];
#pragma unroll
    for (int ks = 0; ks < 2; ++ks)
#pragma unroll
      for (int hi = 0; hi < 4; ++hi)
        vf[ks][hi] = *(const short8*)&Vlds[hi * 16 + l16][ks * 32 + g4 * 8];

#pragma unroll
    for (int qi = 0; qi < 4; ++qi){
      f32x4 sa[4];
#pragma unroll
      for (int kt = 0; kt < 4; ++kt){
        sa[kt] = zero4;
#pragma unroll
        for (int ks = 0; ks < 2; ++ks)
          sa[kt] = __builtin_amdgcn_mfma_f32_16x16x32_bf16(kf[kt][ks], qf[qi][ks], sa[kt], 0, 0, 0);
      }
      float smax = -3.0e38f;
#pragma unroll
      for (int kt = 0; kt < 4; ++kt)
#pragma unroll
        for (int r = 0; r < 4; ++r){
          float s = sa[kt][r] * SC2;
          sa[kt][r] = s;
          smax = fmaxf(smax, s);
        }
      smax = fmaxf(smax, __shfl_xor(smax, 16));
      smax = fmaxf(smax, __shfl_xor(smax, 32));
      float mnew  = fmaxf(m2[qi], smax);
      float alpha = exp2f(m2[qi] - mnew);
      m2[qi] = mnew;
      float psum = 0.f;
      u32 w[4][2];
#pragma unroll
      for (int kt = 0; kt < 4; ++kt){
        float p0 = exp2f(sa[kt][0] - mnew);
        float p1 = exp2f(sa[kt][1] - mnew);
        float p2 = exp2f(sa[kt][2] - mnew);
        float p3 = exp2f(sa[kt][3] - mnew);
        psum += (p0 + p1) + (p2 + p3);
        w[kt][0] = packbf(p0, p1);
        w[kt][1] = packbf(p2, p3);
      }
      psum += __shfl_xor(psum, 16);
      psum += __shfl_xor(psum, 32);
      lsum[qi] = lsum[qi] * alpha + psum;
      u32* prow = (u32*)&Plds[g][l16][0];
#pragma unroll
      for (int kt = 0; kt < 4; ++kt){
        prow[kt * 8 + g4 * 2]     = w[kt][0];
        prow[kt * 8 + g4 * 2 + 1] = w[kt][1];
      }
      float ab[4];
#pragma unroll
      for (int r = 0; r < 4; ++r) ab[r] = __shfl(alpha, g4 * 4 + r);
#pragma unroll
      for (int hi = 0; hi < 4; ++hi)
#pragma unroll
        for (int r = 0; r < 4; ++r) O[qi][hi][r] *= ab[r];
      short8 pa[2];
#pragma unroll
      for (int ks = 0; ks < 2; ++ks)
        pa[ks] = *(const short8*)&Plds[g][l16][ks * 32 + g4 * 8];
#pragma unroll
      for (int hi = 0; hi < 4; ++hi)
#pragma unroll
        for (int ks = 0; ks < 2; ++ks)
          O[qi][hi] = __builtin_amdgcn_mfma_f32_16x16x32_bf16(pa[ks], vf[ks][hi], O[qi][hi], 0, 0, 0);
    }
  }
#pragma unroll
  for (int qi = 0; qi < 4; ++qi){
    float lb[4];
#pragma unroll
    for (int r = 0; r < 4; ++r) lb[r] = 1.0f / __shfl(lsum[qi], g4 * 4 + r);
#pragma unroll
    for (int hi = 0; hi < 4; ++hi)
#pragma unroll
      for (int r = 0; r < 4; ++r){
        int row = rowQ + qi * 16 + g4 * 4 + r;
        int col = qcol + hi * 16 + l16;
        att[(size_t)row * 2048 + col] = f2bf(O[qi][hi][r] * lb[r]);
      }
  }
}

extern "C" void kernel_launch(void* const* d_in, const int* in_sizes, int n_in,
                              void* d_out, int out_size, void* d_ws, size_t ws_size,
                              hipStream_t stream){
  const float* x   = (const float*)d_in[0];
  const float* wq  = (const float*)d_in[1];
  const float* wkv = (const float*)d_in[2];
  const float* wo  = (const float*)d_in[3];
  float* out = (float*)d_out;
  char* ws = (char*)d_ws;

  // workspace layout (67,108,864 B total)
  u16* x_bf  = (u16*)(ws);               // [4096][2048] bf16, 16.78 MB (aliased by att)
  u16* wqkvt = (u16*)(ws + 16777216);    // [3072][2048] bf16, 12.58 MB
  u16* wot   = (u16*)(ws + 29360128);    // [2048][2048] bf16,  8.39 MB
  u16* c1    = (u16*)(ws + 37748736);    // [4096][3072] bf16, 25.17 MB (Q|K|V)
  u16* vt    = (u16*)(ws + 62914560);    // [16*8][64][256] bf16, 4.19 MB
  u16* att   = x_bf;                     // alias: x_bf dead after GEMM1

  k_cvt_bf16<<<4096, 256, 0, stream>>>(x, x_bf, 1048576);
  k_transpose_w<<<4096, 256, 0, stream>>>(wq,  wqkvt,               2048, 2048);
  k_transpose_w<<<2048, 256, 0, stream>>>(wkv, wqkvt + 2048 * 2048, 2048, 1024);
  k_transpose_w<<<4096, 256, 0, stream>>>(wo,  wot,                 2048, 2048);
  // QKV projection: [4096,2048] x [2048,3072] -> c1 bf16. 256x192 tiles, 256 blocks.
  k_gemm8<192, 3, u16><<<256, 512, 0, stream>>>(x_bf, wqkvt, c1, 3072, 2048);
  k_vt<<<512, 256, 0, stream>>>(c1, vt);
  k_attn<<<512, 256, 0, stream>>>(c1, vt, att);
  // output projection: [4096,2048] x [2048,2048] -> f32 out. 256x128 tiles, 256 blocks.
  k_gemm8<128, 2, float><<<256, 512, 0, stream>>>(att, wot, out, 2048, 2048);
}

// Round 5
// 160.633 us; speedup vs baseline: 1.2411x; 1.0548x over previous
//
#include <hip/hip_runtime.h>
#include <stdint.h>

typedef unsigned short u16;
typedef unsigned int   u32;
typedef short short8 __attribute__((ext_vector_type(8)));
typedef float f32x4  __attribute__((ext_vector_type(4)));

// ---------- helpers ----------
__device__ __forceinline__ u16 f2bf(float f){
  u32 u = __builtin_bit_cast(u32, f);
  u32 r = (u + 0x7FFFu + ((u >> 16) & 1u)) >> 16;   // RNE
  return (u16)r;
}
__device__ __forceinline__ u32 packbf(float a, float b){
  return (u32)f2bf(a) | ((u32)f2bf(b) << 16);
}
// async global->LDS, 16B per lane. LDS dest = wave-uniform base + lane*16.
__device__ __forceinline__ void gload16(const u16* g, u16* l){
  __builtin_amdgcn_global_load_lds((const __attribute__((address_space(1))) void*)g,
                                   (__attribute__((address_space(3))) void*)l, 16, 0, 0);
}

// ---------- x f32 -> bf16 ----------
__global__ __launch_bounds__(256) void k_cvt_bf16(const float* __restrict__ x,
                                                  u16* __restrict__ y, int n8){
  int i = blockIdx.x * 256 + threadIdx.x;
  if (i >= n8) return;
  const float4* p = (const float4*)x + (size_t)i * 2;
  float4 a = p[0], b = p[1];
  short8 o;
  o[0] = f2bf(a.x); o[1] = f2bf(a.y); o[2] = f2bf(a.z); o[3] = f2bf(a.w);
  o[4] = f2bf(b.x); o[5] = f2bf(b.y); o[6] = f2bf(b.z); o[7] = f2bf(b.w);
  *(short8*)(y + (size_t)i * 8) = o;
}

// ---------- weight transpose: in f32[R][C] -> out bf16[C][R] ----------
__global__ __launch_bounds__(256) void k_transpose_w(const float* __restrict__ in,
                                                     u16* __restrict__ out, int R, int C){
  __shared__ float tile[32][33];
  int nc = C >> 5;
  int cb = blockIdx.x % nc, rb = blockIdx.x / nc;
  int tx = threadIdx.x & 31, ty = threadIdx.x >> 5;
#pragma unroll
  for (int i = 0; i < 4; ++i){
    int r = rb * 32 + ty + i * 8;
    tile[ty + i * 8][tx] = in[(size_t)r * C + cb * 32 + tx];
  }
  __syncthreads();
#pragma unroll
  for (int i = 0; i < 4; ++i){
    int c = cb * 32 + ty + i * 8;
    out[(size_t)c * R + rb * 32 + tx] = f2bf(tile[tx][ty + i * 8]);
  }
}

// ---------- pipelined GEMM: C[4096][N] = A[4096][K] * Bt[N][K]^T, bf16 in, f32 accum ----
// 512 threads = 8 waves (2m x 4n), BM=256, BK=64, 2 LDS buffers (128-B rows,
// XOR swizzle col^=((row&7)<<4) -> conflict-free ds_read_b128).
// 4 phases per K-tile; each phase's MFMA consumes frags read during the PREVIOUS
// phase; staging for kt+1 issued in phases a/b (issue-early), vmcnt(0) drain at
// phase d (~3 phases of cover), one barrier per phase, setprio around MFMA.
template<int BN, int NFRAG, int BLOADS, typename CT>
__global__ __launch_bounds__(512, 2) void k_gemm8p(const u16* __restrict__ A,
                                                   const u16* __restrict__ Bt,
                                                   CT* __restrict__ C,
                                                   int N, int K){
  constexpr int SZA = 256 * 128;        // A bytes per buffer
  constexpr int SZB = BN * 128;         // B bytes per buffer
  constexpr int SZ  = SZA + SZB;
  constexpr int WT_N = BN / 4;
  __shared__ char lds[2 * SZ];

  int tid = threadIdx.x, lane = tid & 63, wid = tid >> 6;
  int l16 = lane & 15, g4 = lane >> 4;
  int wm = wid >> 2, wn = wid & 3;
  // XCD swizzle: 256 blocks / 8 XCDs -> 32 contiguous wg per XCD
  int bid = blockIdx.x;
  int wg = (bid & 7) * 32 + (bid >> 3);
  int bm = wg >> 4, bn = wg & 15;

  const u16* baseA = A  + (size_t)(bm * 256) * K;
  const u16* baseB = Bt + (size_t)(bn * BN) * K;

  // staging maps: linear LDS dest q; global source col inverse-swizzled (involution)
  int aLds[4], aG[4];
#pragma unroll
  for (int i = 0; i < 4; ++i){
    int q = (wid * 4 + i) * 1024 + lane * 16;
    int row = q >> 7, c = q & 127;
    int cs = c ^ ((row & 7) << 4);
    aLds[i] = q; aG[i] = row * K + (cs >> 1);
  }
  int bLds[BLOADS], bG[BLOADS];
#pragma unroll
  for (int j = 0; j < BLOADS; ++j){
    int q = (wid * BLOADS + j) * 1024 + lane * 16;
    int row = q >> 7, c = q & 127;
    int cs = c ^ ((row & 7) << 4);
    bLds[j] = q; bG[j] = row * K + (cs >> 1);
  }
  auto stageA = [&](int t){
    char* dst = lds + (t & 1) * SZ;
#pragma unroll
    for (int i = 0; i < 4; ++i) gload16(baseA + aG[i] + t * 64, (u16*)(dst + aLds[i]));
  };
  auto stageB = [&](int t){
    char* dst = lds + (t & 1) * SZ + SZA;
#pragma unroll
    for (int j = 0; j < BLOADS; ++j) gload16(baseB + bG[j] + t * 64, (u16*)(dst + bLds[j]));
  };
  auto rdA = [&](const char* Ab, int m, int ks){
    int row = wm * 128 + m * 16 + l16;
    return *(const short8*)(Ab + row * 128 + ((ks * 64 + g4 * 16) ^ ((row & 7) << 4)));
  };
  auto rdB = [&](const char* Bb, int nf, int ks){
    int row = wn * WT_N + nf * 16 + l16;
    return *(const short8*)(Bb + row * 128 + ((ks * 64 + g4 * 16) ^ ((row & 7) << 4)));
  };

  f32x4 zero4 = {0.f, 0.f, 0.f, 0.f};
  f32x4 acc[8][NFRAG];
#pragma unroll
  for (int i = 0; i < 8; ++i)
#pragma unroll
    for (int j = 0; j < NFRAG; ++j) acc[i][j] = zero4;

  int NK = K >> 6;
  // prologue: stage tile 0, drain
  stageA(0); stageB(0);
  asm volatile("s_waitcnt vmcnt(0)" ::: "memory");

  for (int kt = 0; kt < NK; ++kt){
    const char* Ab = lds + (kt & 1) * SZ;
    const char* Bb = Ab + SZA;
    bool st = (kt + 1 < NK);
    __builtin_amdgcn_s_barrier();
    // ---- phase a: read {bf0, a0}; stage A(kt+1); read a1; MFMA(a0 x bf0, ks0 m0-3)
    short8 bf0[NFRAG], a0[4], a1[4], bf1[NFRAG], a2[4], a3[4];
#pragma unroll
    for (int nf = 0; nf < NFRAG; ++nf) bf0[nf] = rdB(Bb, nf, 0);
#pragma unroll
    for (int m = 0; m < 4; ++m) a0[m] = rdA(Ab, m, 0);
    if (st) stageA(kt + 1);
#pragma unroll
    for (int m = 0; m < 4; ++m) a1[m] = rdA(Ab, 4 + m, 0);
    __builtin_amdgcn_s_setprio(1);
#pragma unroll
    for (int m = 0; m < 4; ++m)
#pragma unroll
      for (int nf = 0; nf < NFRAG; ++nf)
        acc[m][nf] = __builtin_amdgcn_mfma_f32_16x16x32_bf16(a0[m], bf0[nf], acc[m][nf], 0, 0, 0);
    __builtin_amdgcn_s_setprio(0);
    __builtin_amdgcn_s_barrier();
    // ---- phase b: stage B(kt+1); read {bf1, a2}; MFMA(a1 x bf0, ks0 m4-7)
    if (st) stageB(kt + 1);
#pragma unroll
    for (int nf = 0; nf < NFRAG; ++nf) bf1[nf] = rdB(Bb, nf, 1);
#pragma unroll
    for (int m = 0; m < 4; ++m) a2[m] = rdA(Ab, m, 1);
    __builtin_amdgcn_s_setprio(1);
#pragma unroll
    for (int m = 0; m < 4; ++m)
#pragma unroll
      for (int nf = 0; nf < NFRAG; ++nf)
        acc[4 + m][nf] = __builtin_amdgcn_mfma_f32_16x16x32_bf16(a1[m], bf0[nf], acc[4 + m][nf], 0, 0, 0);
    __builtin_amdgcn_s_setprio(0);
    __builtin_amdgcn_s_barrier();
    // ---- phase c: read a3; MFMA(a2 x bf1, ks1 m0-3)
#pragma unroll
    for (int m = 0; m < 4; ++m) a3[m] = rdA(Ab, 4 + m, 1);
    __builtin_amdgcn_s_setprio(1);
#pragma unroll
    for (int m = 0; m < 4; ++m)
#pragma unroll
      for (int nf = 0; nf < NFRAG; ++nf)
        acc[m][nf] = __builtin_amdgcn_mfma_f32_16x16x32_bf16(a2[m], bf1[nf], acc[m][nf], 0, 0, 0);
    __builtin_amdgcn_s_setprio(0);
    __builtin_amdgcn_s_barrier();
    // ---- phase d: MFMA(a3 x bf1, ks1 m4-7); drain next tile's staging (issued ~3 phases ago)
    __builtin_amdgcn_s_setprio(1);
#pragma unroll
    for (int m = 0; m < 4; ++m)
#pragma unroll
      for (int nf = 0; nf < NFRAG; ++nf)
        acc[4 + m][nf] = __builtin_amdgcn_mfma_f32_16x16x32_bf16(a3[m], bf1[nf], acc[4 + m][nf], 0, 0, 0);
    __builtin_amdgcn_s_setprio(0);
    if (st) asm volatile("s_waitcnt vmcnt(0)" ::: "memory");
  }

#pragma unroll
  for (int mf = 0; mf < 8; ++mf)
#pragma unroll
    for (int nf = 0; nf < NFRAG; ++nf)
#pragma unroll
      for (int r = 0; r < 4; ++r){
        int row = bm * 256 + wm * 128 + mf * 16 + g4 * 4 + r;
        int col = bn * BN + wn * WT_N + nf * 16 + l16;
        float vv = acc[mf][nf][r];
        if constexpr (sizeof(CT) == 2) C[(size_t)row * N + col] = (CT)f2bf(vv);
        else                           C[(size_t)row * N + col] = (CT)vv;
      }
}

// ---------- V transpose: c1 V-part [bv*256+s][2560+n*64+h] -> vt[(bv*8+n)*64+h][256 s] ----------
__global__ __launch_bounds__(256) void k_vt(const u16* __restrict__ c1, u16* __restrict__ vt){
  __shared__ u16 tile[64][72];
  int bid = blockIdx.x;
  int st = bid & 3, n = (bid >> 2) & 7, bv = bid >> 5;   // bv = b*8+v (0..15)
  int t = threadIdx.x;
  int sr = t >> 2, sc = t & 3;
  const u16* src = c1 + (size_t)(bv * 256 + st * 64 + sr) * 3072 + 2560 + n * 64 + sc * 16;
  short8 a = *(const short8*)src;
  short8 b = *(const short8*)(src + 8);
  *(short8*)&tile[sr][sc * 16]     = a;
  *(short8*)&tile[sr][sc * 16 + 8] = b;
  __syncthreads();
  int h = t >> 2, c2 = t & 3;
  short8 o0, o1;
#pragma unroll
  for (int j = 0; j < 8; ++j) o0[j] = (short)tile[c2 * 16 + j][h];
#pragma unroll
  for (int j = 0; j < 8; ++j) o1[j] = (short)tile[c2 * 16 + 8 + j][h];
  u16* dst = vt + (size_t)((bv * 8 + n) * 64 + h) * 256 + st * 64 + c2 * 16;
  *(short8*)dst       = o0;
  *(short8*)(dst + 8) = o1;
}

// ---------- fused GQA neighbor attention ----------
__global__ __launch_bounds__(256, 2) void k_attn(const u16* __restrict__ c1,
                                                 const u16* __restrict__ vt,
                                                 u16* __restrict__ att){
  __shared__ u16 Klds[64][72];
  __shared__ u16 Vlds[64][72];
  __shared__ u16 Plds[4][16][72];
  int bid = blockIdx.x;
  int qt = bid & 3, n = (bid >> 2) & 7, v = (bid >> 5) & 7, b = bid >> 8;
  int tid = threadIdx.x;
  int g = tid >> 6, lane = tid & 63, l16 = lane & 15, g4 = lane >> 4;
  int bv = b * 8 + v;
  int rowQ = bv * 256 + qt * 64;
  int qcol = n * 256 + g * 64;
  const float SC2 = 0.18033688011112042f;   // log2(e)/8

  short8 qf[4][2];
#pragma unroll
  for (int qi = 0; qi < 4; ++qi)
#pragma unroll
    for (int kk = 0; kk < 2; ++kk)
      qf[qi][kk] = *(const short8*)(c1 + (size_t)(rowQ + qi * 16 + l16) * 3072
                                     + qcol + kk * 32 + g4 * 8);

  f32x4 zero4 = {0.f, 0.f, 0.f, 0.f};
  f32x4 O[4][4];
#pragma unroll
  for (int i = 0; i < 4; ++i)
#pragma unroll
    for (int j = 0; j < 4; ++j) O[i][j] = zero4;
  float m2[4]   = {-3.0e38f, -3.0e38f, -3.0e38f, -3.0e38f};
  float lsum[4] = {0.f, 0.f, 0.f, 0.f};

  int sr = tid >> 2, sc = tid & 3;
  short8 k0, k1, v0, v1;
  {
    int vn = (v + 7) & 7;
    const u16* ks = c1 + (size_t)((b * 8 + vn) * 256 + sr) * 3072 + 2048 + n * 64 + sc * 16;
    k0 = *(const short8*)ks; k1 = *(const short8*)(ks + 8);
    const u16* vs = vt + (size_t)(((b * 8 + vn) * 8 + n) * 64 + sr) * 256 + sc * 16;
    v0 = *(const short8*)vs; v1 = *(const short8*)(vs + 8);
  }

  for (int ti = 0; ti < 8; ++ti){
    __syncthreads();
    *(short8*)&Klds[sr][sc * 16]     = k0;
    *(short8*)&Klds[sr][sc * 16 + 8] = k1;
    *(short8*)&Vlds[sr][sc * 16]     = v0;
    *(short8*)&Vlds[sr][sc * 16 + 8] = v1;
    __syncthreads();
    if (ti < 7){
      int tn = ti + 1;
      int vn = (tn < 4) ? ((v + 7) & 7) : ((v + 1) & 7);
      int tb = (tn & 3) * 64;
      const u16* ks = c1 + (size_t)((b * 8 + vn) * 256 + tb + sr) * 3072 + 2048 + n * 64 + sc * 16;
      k0 = *(const short8*)ks; k1 = *(const short8*)(ks + 8);
      const u16* vs = vt + (size_t)(((b * 8 + vn) * 8 + n) * 64 + sr) * 256 + tb + sc * 16;
      v0 = *(const short8*)vs; v1 = *(const short8*)(vs + 8);
    }
    short8 kf[4][2], vf[2][4];
#pragma unroll
    for (int kt = 0; kt < 4; ++kt)
#pragma unroll
      for (int ks = 0; ks < 2; ++ks)
        kf[kt][ks] = *(const short8*)&Klds[kt * 16 + l16][ks * 32 + g4 * 8];
#pragma unroll
    for (int ks = 0; ks < 2; ++ks)
#pragma unroll
      for (int hi = 0; hi < 4; ++hi)
        vf[ks][hi] = *(const short8*)&Vlds[hi * 16 + l16][ks * 32 + g4 * 8];

#pragma unroll
    for (int qi = 0; qi < 4; ++qi){
      f32x4 sa[4];
#pragma unroll
      for (int kt = 0; kt < 4; ++kt){
        sa[kt] = zero4;
#pragma unroll
        for (int ks = 0; ks < 2; ++ks)
          sa[kt] = __builtin_amdgcn_mfma_f32_16x16x32_bf16(kf[kt][ks], qf[qi][ks], sa[kt], 0, 0, 0);
      }
      float smax = -3.0e38f;
#pragma unroll
      for (int kt = 0; kt < 4; ++kt)
#pragma unroll
        for (int r = 0; r < 4; ++r){
          float s = sa[kt][r] * SC2;
          sa[kt][r] = s;
          smax = fmaxf(smax, s);
        }
      smax = fmaxf(smax, __shfl_xor(smax, 16));
      smax = fmaxf(smax, __shfl_xor(smax, 32));
      float mnew  = fmaxf(m2[qi], smax);
      float alpha = exp2f(m2[qi] - mnew);
      m2[qi] = mnew;
      float psum = 0.f;
      u32 w[4][2];
#pragma unroll
      for (int kt = 0; kt < 4; ++kt){
        float p0 = exp2f(sa[kt][0] - mnew);
        float p1 = exp2f(sa[kt][1] - mnew);
        float p2 = exp2f(sa[kt][2] - mnew);
        float p3 = exp2f(sa[kt][3] - mnew);
        psum += (p0 + p1) + (p2 + p3);
        w[kt][0] = packbf(p0, p1);
        w[kt][1] = packbf(p2, p3);
      }
      psum += __shfl_xor(psum, 16);
      psum += __shfl_xor(psum, 32);
      lsum[qi] = lsum[qi] * alpha + psum;
      u32* prow = (u32*)&Plds[g][l16][0];
#pragma unroll
      for (int kt = 0; kt < 4; ++kt){
        prow[kt * 8 + g4 * 2]     = w[kt][0];
        prow[kt * 8 + g4 * 2 + 1] = w[kt][1];
      }
      float ab[4];
#pragma unroll
      for (int r = 0; r < 4; ++r) ab[r] = __shfl(alpha, g4 * 4 + r);
#pragma unroll
      for (int hi = 0; hi < 4; ++hi)
#pragma unroll
        for (int r = 0; r < 4; ++r) O[qi][hi][r] *= ab[r];
      short8 pa[2];
#pragma unroll
      for (int ks = 0; ks < 2; ++ks)
        pa[ks] = *(const short8*)&Plds[g][l16][ks * 32 + g4 * 8];
#pragma unroll
      for (int hi = 0; hi < 4; ++hi)
#pragma unroll
        for (int ks = 0; ks < 2; ++ks)
          O[qi][hi] = __builtin_amdgcn_mfma_f32_16x16x32_bf16(pa[ks], vf[ks][hi], O[qi][hi], 0, 0, 0);
    }
  }
#pragma unroll
  for (int qi = 0; qi < 4; ++qi){
    float lb[4];
#pragma unroll
    for (int r = 0; r < 4; ++r) lb[r] = 1.0f / __shfl(lsum[qi], g4 * 4 + r);
#pragma unroll
    for (int hi = 0; hi < 4; ++hi)
#pragma unroll
      for (int r = 0; r < 4; ++r){
        int row = rowQ + qi * 16 + g4 * 4 + r;
        int col = qcol + hi * 16 + l16;
        att[(size_t)row * 2048 + col] = f2bf(O[qi][hi][r] * lb[r]);
      }
  }
}

extern "C" void kernel_launch(void* const* d_in, const int* in_sizes, int n_in,
                              void* d_out, int out_size, void* d_ws, size_t ws_size,
                              hipStream_t stream){
  const float* x   = (const float*)d_in[0];
  const float* wq  = (const float*)d_in[1];
  const float* wkv = (const float*)d_in[2];
  const float* wo  = (const float*)d_in[3];
  float* out = (float*)d_out;
  char* ws = (char*)d_ws;

  // workspace layout (67,108,864 B total)
  u16* x_bf  = (u16*)(ws);               // [4096][2048] bf16, 16.78 MB (aliased by att)
  u16* wqkvt = (u16*)(ws + 16777216);    // [3072][2048] bf16, 12.58 MB
  u16* wot   = (u16*)(ws + 29360128);    // [2048][2048] bf16,  8.39 MB
  u16* c1    = (u16*)(ws + 37748736);    // [4096][3072] bf16, 25.17 MB (Q|K|V)
  u16* vt    = (u16*)(ws + 62914560);    // [16*8][64][256] bf16, 4.19 MB
  u16* att   = x_bf;                     // alias: x_bf dead after GEMM1

  k_cvt_bf16<<<4096, 256, 0, stream>>>(x, x_bf, 1048576);
  k_transpose_w<<<4096, 256, 0, stream>>>(wq,  wqkvt,               2048, 2048);
  k_transpose_w<<<2048, 256, 0, stream>>>(wkv, wqkvt + 2048 * 2048, 2048, 1024);
  k_transpose_w<<<4096, 256, 0, stream>>>(wo,  wot,                 2048, 2048);
  // QKV projection: [4096,2048] x [2048,3072] -> c1 bf16. 256x192 tiles, 256 blocks.
  k_gemm8p<192, 3, 3, u16><<<256, 512, 0, stream>>>(x_bf, wqkvt, c1, 3072, 2048);
  k_vt<<<512, 256, 0, stream>>>(c1, vt);
  k_attn<<<512, 256, 0, stream>>>(c1, vt, att);
  // output projection: [4096,2048] x [2048,2048] -> f32 out. 256x128 tiles, 256 blocks.
  k_gemm8p<128, 2, 2, float><<<256, 512, 0, stream>>>(att, wot, out, 2048, 2048);
}